// Round 2
// baseline (18431.662 us; speedup 1.0000x reference)
//
#include <hip/hip_runtime.h>
#include <stdint.h>

typedef uint32_t u32;
typedef uint16_t u16;

#define DEV static __device__ __forceinline__

#define BATCH 512
#define CD    64
#define ZL    16
#define HID   512
#define H2D   256
#define NC    9
#define SLEN  64
#define L1    35
#define KIN1  274   /* NC + H2D + NC */

#define JAX_PARTITIONABLE 1

// ---------------- Threefry-2x32 (JAX key schedule, 20 rounds) ----------------
DEV void threefry2x32(u32 k0, u32 k1, u32 x0, u32 x1, u32 &o0, u32 &o1){
  const u32 ks2 = k0 ^ k1 ^ 0x1BD11BDAu;
#define TF_R(d) { x0 += x1; x1 = (x1 << (d)) | (x1 >> (32 - (d))); x1 ^= x0; }
  x0 += k0; x1 += k1;
  TF_R(13) TF_R(15) TF_R(26) TF_R(6)
  x0 += k1;  x1 += ks2 + 1u;
  TF_R(17) TF_R(29) TF_R(16) TF_R(24)
  x0 += ks2; x1 += k0 + 2u;
  TF_R(13) TF_R(15) TF_R(26) TF_R(6)
  x0 += k0;  x1 += k1 + 3u;
  TF_R(17) TF_R(29) TF_R(16) TF_R(24)
  x0 += k1;  x1 += ks2 + 4u;
  TF_R(13) TF_R(15) TF_R(26) TF_R(6)
  x0 += ks2; x1 += k0 + 5u;
#undef TF_R
  o0 = x0; o1 = x1;
}

// key for scan step t: keys = jax.random.split(jax.random.key(42), 64)
DEV void step_key(int t, u32 &ka, u32 &kb){
#if JAX_PARTITIONABLE
  threefry2x32(0u, 42u, 0u, (u32)t, ka, kb);   // foldlike split: 64b iota -> (hi=0, lo=t)
#else
  u32 j0 = 2u*(u32)t, j1 = j0 + 1u, a0, a1;
  if (j0 < 64u){ threefry2x32(0u,42u, j0, 64u+j0, a0, a1); ka = a0; }
  else         { threefry2x32(0u,42u, j0-64u, j0, a0, a1); ka = a1; }
  if (j1 < 64u){ threefry2x32(0u,42u, j1, 64u+j1, a0, a1); kb = a0; }
  else         { threefry2x32(0u,42u, j1-64u, j1, a0, a1); kb = a1; }
#endif
}

// r = jax.random.uniform(key, (512,9))[flat f]
DEV float rng_uniform(u32 ka, u32 kb, u32 f){
  u32 bits, o0, o1;
#if JAX_PARTITIONABLE
  threefry2x32(ka, kb, 0u, f, o0, o1);   // partitionable 32-bit bits: o0 ^ o1
  bits = o0 ^ o1;
#else
  const u32 HALF = (u32)(BATCH * NC / 2); // 2304
  if (f < HALF){ threefry2x32(ka, kb, f, f + HALF, o0, o1); bits = o0; }
  else         { threefry2x32(ka, kb, f - HALF, f, o0, o1); bits = o1; }
#endif
  u32 fb = (bits >> 9) | 0x3F800000u;
  float fv; __builtin_memcpy(&fv, &fb, 4);
  return fv - 1.0f;
}

// ---------------- ConvT1 (64->512, k=4, s=2, opad=1) + BN + LReLU ----------------
// out[b,o,t] = sum_{k: t-k even, s=(t-k)/2 in [0,16)} sum_i z[b,i,s]*w[i,o,k]
__global__ __launch_bounds__(256) void k_conv1(
    const float* __restrict__ z, const float* __restrict__ w1, const float* __restrict__ b1,
    const float* __restrict__ g1, const float* __restrict__ bt1, const float* __restrict__ m1,
    const float* __restrict__ v1, float* __restrict__ y1out)
{
  int t = blockIdx.x;            // 0..34
  int bg = blockIdx.y * 8;       // batch group of 8
  int tid = threadIdx.x;
  __shared__ float zsh[2][8][CD];
  int k0 = t & 1;
  int sA = (t - k0) >> 1, sB = sA - 1;
  bool vA = (sA >= 0 && sA < ZL), vB = (sB >= 0 && sB < ZL);
  for (int l = tid; l < 2*8*CD; l += 256){
    int p = l >> 9, bb = (l >> 6) & 7, i = l & 63;
    int s = p ? sB : sA; bool v = p ? vB : vA;
    zsh[p][bb][i] = v ? z[((bg + bb)*CD + i)*ZL + s] : 0.f;
  }
  __syncthreads();
  const float4* w1v = (const float4*)w1;  // idx = i*HID + o -> taps k=0..3
  for (int o = tid; o < HID; o += 256){
    float acc[8] = {0,0,0,0,0,0,0,0};
    for (int i = 0; i < CD; i++){
      float4 wv = w1v[i*HID + o];
      float wA = k0 ? wv.y : wv.x;   // k = k0
      float wB = k0 ? wv.w : wv.z;   // k = k0+2
      #pragma unroll
      for (int bb = 0; bb < 8; bb++)
        acc[bb] += zsh[0][bb][i]*wA + zsh[1][bb][i]*wB;
    }
    float xb = b1[o];
    float sc = g1[o] / sqrtf(v1[o] + 1e-5f);
    float mm = m1[o], be = bt1[o];
    #pragma unroll
    for (int bb = 0; bb < 8; bb++){
      float y = (acc[bb] + xb - mm)*sc + be;
      y = (y > 0.f) ? y : 0.2f*y;
      y1out[((bg + bb)*L1 + t)*HID + o] = y;
    }
  }
}

// ---------------- ConvT2 (512->256, k=4, s=2) + BN + LReLU -> x[b][t][c], t<64 ----
__global__ __launch_bounds__(256) void k_conv2(
    const float* __restrict__ y1, const float* __restrict__ w2, const float* __restrict__ b2,
    const float* __restrict__ g2, const float* __restrict__ bt2, const float* __restrict__ m2,
    const float* __restrict__ v2, float* __restrict__ xin)
{
  int t = blockIdx.x;            // 0..63
  int bg = blockIdx.y * 8;
  int tid = threadIdx.x;         // c = tid (0..255)
  __shared__ float ysh[2][8][HID];  // 32 KB
  int k0 = t & 1;
  int sA = (t - k0) >> 1, sB = sA - 1;   // sA always valid (<=31<35); sB valid if >=0
  bool vB = (sB >= 0);
  for (int l = tid; l < 2*8*HID; l += 256){
    int p = l >> 12, bb = (l >> 9) & 7, o = l & 511;
    int s = p ? sB : sA; bool v = p ? vB : true;
    ysh[p][bb][o] = v ? y1[((bg + bb)*L1 + s)*HID + o] : 0.f;
  }
  __syncthreads();
  int c = tid;
  float acc[8] = {0,0,0,0,0,0,0,0};
  const float4* w2v = (const float4*)w2;  // idx = o*H2D + c
  for (int o4 = 0; o4 < HID; o4 += 4){
    float wA[4], wB[4];
    #pragma unroll
    for (int j = 0; j < 4; j++){
      float4 wv = w2v[(o4 + j)*H2D + c];
      wA[j] = k0 ? wv.y : wv.x;
      wB[j] = k0 ? wv.w : wv.z;
    }
    #pragma unroll
    for (int bb = 0; bb < 8; bb++){
      const float4 ya = *(const float4*)&ysh[0][bb][o4];
      const float4 yb = *(const float4*)&ysh[1][bb][o4];
      acc[bb] += ya.x*wA[0] + ya.y*wA[1] + ya.z*wA[2] + ya.w*wA[3]
               + yb.x*wB[0] + yb.y*wB[1] + yb.z*wB[2] + yb.w*wB[3];
    }
  }
  float xb = b2[c];
  float sc = g2[c] / sqrtf(v2[c] + 1e-5f);
  float mm = m2[c], be = bt2[c];
  #pragma unroll
  for (int bb = 0; bb < 8; bb++){
    float y = (acc[bb] + xb - mm)*sc + be;
    y = (y > 0.f) ? y : 0.2f*y;
    xin[((bg + bb)*SLEN + t)*H2D + c] = y;
  }
}

// ---------------- h1_0 = skel_encoded @ hfc_w.T + hfc_b;  zero out_prev ----------
__global__ __launch_bounds__(256) void k_h0(
    const float* __restrict__ se, const float* __restrict__ w, const float* __restrict__ bias,
    float* __restrict__ h1, float* __restrict__ outp)
{
  int b = blockIdx.x, tid = threadIdx.x;
  __shared__ float ssh[HID];
  for (int i = tid; i < HID; i += 256) ssh[i] = se[b*HID + i];
  __syncthreads();
  for (int j = tid; j < HID; j += 256){
    float acc = 0.f;
    for (int q = 0; q < HID; q++) acc += ssh[q] * w[j*HID + q];
    h1[b*HID + j] = acc + bias[j];
  }
  if (tid < 16) outp[b*16 + tid] = 0.f;
}

// ---------------- fused GRU cell: dual GEMM + gates -------------------------------
// MODE 0: A1 = cat(out_prev, x_t, skel_t) K=274; A2=hprev(h1) K=512 -> hout=h1'
// MODE 1: A1 = h1_new K=512; A2=hprev(h2 or h1 at t=0) K=512 -> hout=h2'
template<int MODE>
__global__ __launch_bounds__(256) void k_gru(
    const float* __restrict__ xin, const float* __restrict__ skel, const float* __restrict__ outp,
    const float* __restrict__ a1src, const float* __restrict__ hprev,
    const float* __restrict__ wih, const float* __restrict__ whh,
    const float* __restrict__ bih, const float* __restrict__ bhh,
    float* __restrict__ hout, int t)
{
  const int KA = (MODE == 0) ? KIN1 : HID;
  int jt = blockIdx.x * 32, bt = blockIdx.y * 32;
  int tid = threadIdx.x;
  int tn = tid & 15, tm = tid >> 4;
  __shared__ float As[32][18];
  __shared__ float Ws[3][32][18];
  float ai[3][2][2] = {{{0}}};
  float ah[3][2][2] = {{{0}}};

  // phase 1: A1 @ wih.T (3 gate slices)
  for (int kc = 0; kc < KA; kc += 16){
    for (int l = tid; l < 512; l += 256){
      int mm = l >> 4, kk = l & 15; int k = kc + kk; int mg = bt + mm;
      float v = 0.f;
      if (k < KA){
        if (MODE == 0){
          if (k < NC)            v = outp[mg*16 + k];
          else if (k < NC + H2D) v = xin[(mg*SLEN + t)*H2D + (k - NC)];
          else                   v = skel[(mg*SLEN + t)*NC + (k - NC - H2D)];
        } else {
          v = a1src[mg*HID + k];
        }
      }
      As[mm][kk] = v;
    }
    for (int l = tid; l < 1536; l += 256){
      int g = l >> 9, rem = l & 511, nn = rem >> 4, kk = rem & 15; int k = kc + kk;
      int ng = jt + nn + g*HID;
      Ws[g][nn][kk] = (k < KA) ? wih[ng*KA + k] : 0.f;
    }
    __syncthreads();
    #pragma unroll
    for (int kk = 0; kk < 16; kk += 2){
      float2 a0 = *(const float2*)&As[tm][kk];
      float2 a1 = *(const float2*)&As[tm+16][kk];
      #pragma unroll
      for (int g = 0; g < 3; g++){
        float2 w0 = *(const float2*)&Ws[g][tn][kk];
        float2 w1 = *(const float2*)&Ws[g][tn+16][kk];
        ai[g][0][0] += a0.x*w0.x + a0.y*w0.y;
        ai[g][0][1] += a0.x*w1.x + a0.y*w1.y;
        ai[g][1][0] += a1.x*w0.x + a1.y*w0.y;
        ai[g][1][1] += a1.x*w1.x + a1.y*w1.y;
      }
    }
    __syncthreads();
  }
  // phase 2: hprev @ whh.T
  for (int kc = 0; kc < HID; kc += 16){
    for (int l = tid; l < 512; l += 256){
      int mm = l >> 4, kk = l & 15; int mg = bt + mm;
      As[mm][kk] = hprev[mg*HID + kc + kk];
    }
    for (int l = tid; l < 1536; l += 256){
      int g = l >> 9, rem = l & 511, nn = rem >> 4, kk = rem & 15;
      int ng = jt + nn + g*HID;
      Ws[g][nn][kk] = whh[ng*HID + kc + kk];
    }
    __syncthreads();
    #pragma unroll
    for (int kk = 0; kk < 16; kk += 2){
      float2 a0 = *(const float2*)&As[tm][kk];
      float2 a1 = *(const float2*)&As[tm+16][kk];
      #pragma unroll
      for (int g = 0; g < 3; g++){
        float2 w0 = *(const float2*)&Ws[g][tn][kk];
        float2 w1 = *(const float2*)&Ws[g][tn+16][kk];
        ah[g][0][0] += a0.x*w0.x + a0.y*w0.y;
        ah[g][0][1] += a0.x*w1.x + a0.y*w1.y;
        ah[g][1][0] += a1.x*w0.x + a1.y*w0.y;
        ah[g][1][1] += a1.x*w1.x + a1.y*w1.y;
      }
    }
    __syncthreads();
  }
  // epilogue: gates (torch GRUCell order r,z,n)
  #pragma unroll
  for (int mi = 0; mi < 2; mi++){
    #pragma unroll
    for (int ni = 0; ni < 2; ni++){
      int mg = bt + tm + mi*16, ng = jt + tn + ni*16;
      float gir = ai[0][mi][ni] + bih[ng];
      float giz = ai[1][mi][ni] + bih[ng + 512];
      float gin = ai[2][mi][ni] + bih[ng + 1024];
      float ghr = ah[0][mi][ni] + bhh[ng];
      float ghz = ah[1][mi][ni] + bhh[ng + 512];
      float ghn = ah[2][mi][ni] + bhh[ng + 1024];
      float r  = 1.f / (1.f + expf(-(gir + ghr)));
      float zz = 1.f / (1.f + expf(-(giz + ghz)));
      float nn = tanhf(gin + r * ghn);
      float hp = hprev[mg*HID + ng];
      hout[mg*HID + ng] = (1.f - zz)*nn + zz*hp;
    }
  }
}

// ---------------- logits = h2 @ nfc_w.T + nfc_b; write f32; sample feedback ------
__global__ __launch_bounds__(288) void k_logits(
    const float* __restrict__ h2, const float* __restrict__ nw, const float* __restrict__ nb,
    float* __restrict__ dout, float* __restrict__ outp, int t)
{
  int b = blockIdx.x, tid = threadIdx.x;  // 288 = 9 groups x 32 lanes
  __shared__ float hsh[HID];
  __shared__ float lsh[NC];
  for (int i = tid; i < HID; i += 288) hsh[i] = h2[b*HID + i];
  __syncthreads();
  int c = tid >> 5, l = tid & 31;
  float acc = 0.f;
  for (int q = l; q < HID; q += 32) acc += hsh[q] * nw[c*HID + q];
  for (int off = 16; off; off >>= 1) acc += __shfl_down(acc, off, 32);
  if (l == 0) lsh[c] = acc + nb[c];
  __syncthreads();
  if (tid < NC){
    float logit = lsh[tid];
    dout[(b*SLEN + t)*NC + tid] = logit;
    u32 ka, kb; step_key(t, ka, kb);
    float r = rng_uniform(ka, kb, (u32)(b*NC + tid));
    float s = 1.f / (1.f + expf(-logit));
    outp[b*16 + tid] = (s - r > 0.f) ? 1.f : 0.f;
  }
}

// ---------------- host ----------------
extern "C" void kernel_launch(void* const* d_in, const int* in_sizes, int n_in,
                              void* d_out, int out_size, void* d_ws, size_t ws_size,
                              hipStream_t stream) {
  (void)in_sizes; (void)n_in; (void)out_size; (void)ws_size;
  const float* z       = (const float*)d_in[0];
  const float* skel    = (const float*)d_in[2];
  const float* se      = (const float*)d_in[3];
  const float* ct1_w   = (const float*)d_in[6];
  const float* ct1_b   = (const float*)d_in[7];
  const float* bn1_g   = (const float*)d_in[8];
  const float* bn1_b   = (const float*)d_in[9];
  const float* bn1_m   = (const float*)d_in[10];
  const float* bn1_v   = (const float*)d_in[11];
  const float* ct2_w   = (const float*)d_in[12];
  const float* ct2_b   = (const float*)d_in[13];
  const float* bn2_g   = (const float*)d_in[14];
  const float* bn2_b   = (const float*)d_in[15];
  const float* bn2_m   = (const float*)d_in[16];
  const float* bn2_v   = (const float*)d_in[17];
  const float* hfc_w   = (const float*)d_in[18];
  const float* hfc_b   = (const float*)d_in[19];
  const float* g1_wih  = (const float*)d_in[20];
  const float* g1_whh  = (const float*)d_in[21];
  const float* g1_bih  = (const float*)d_in[22];
  const float* g1_bhh  = (const float*)d_in[23];
  const float* g2_wih  = (const float*)d_in[24];
  const float* g2_whh  = (const float*)d_in[25];
  const float* g2_bih  = (const float*)d_in[26];
  const float* g2_bhh  = (const float*)d_in[27];
  const float* nfc_w   = (const float*)d_in[28];
  const float* nfc_b   = (const float*)d_in[29];

  float* ws  = (float*)d_ws;
  float* y1  = ws;                                   // 512*35*512
  float* xin = y1  + (size_t)BATCH*L1*HID;           // 512*64*256
  float* h1a = xin + (size_t)BATCH*SLEN*H2D;
  float* h1b = h1a + (size_t)BATCH*HID;
  float* h2a = h1b + (size_t)BATCH*HID;
  float* h2b = h2a + (size_t)BATCH*HID;
  float* outp= h2b + (size_t)BATCH*HID;              // 512*16
  float* dout= (float*)d_out;

  k_conv1<<<dim3(L1, BATCH/8), 256, 0, stream>>>(z, ct1_w, ct1_b, bn1_g, bn1_b, bn1_m, bn1_v, y1);
  k_conv2<<<dim3(SLEN, BATCH/8), 256, 0, stream>>>(y1, ct2_w, ct2_b, bn2_g, bn2_b, bn2_m, bn2_v, xin);
  k_h0<<<BATCH, 256, 0, stream>>>(se, hfc_w, hfc_b, h1a, outp);

  for (int t = 0; t < SLEN; t++){
    float* h1cur = (t & 1) ? h1b : h1a;
    float* h1nxt = (t & 1) ? h1a : h1b;
    float* h2cur = (t & 1) ? h2b : h2a;
    float* h2nxt = (t & 1) ? h2a : h2b;
    k_gru<0><<<dim3(16,16), 256, 0, stream>>>(xin, skel, outp, (const float*)nullptr, h1cur,
                                              g1_wih, g1_whh, g1_bih, g1_bhh, h1nxt, t);
    const float* h2prev = (t == 0) ? h1nxt : h2cur;
    k_gru<1><<<dim3(16,16), 256, 0, stream>>>((const float*)nullptr, (const float*)nullptr,
                                              (const float*)nullptr, h1nxt, h2prev,
                                              g2_wih, g2_whh, g2_bih, g2_bhh, h2nxt, t);
    k_logits<<<BATCH, 288, 0, stream>>>(h2nxt, nfc_w, nfc_b, dout, outp, t);
  }
}

// Round 3
// 18040.950 us; speedup vs baseline: 1.0217x; 1.0217x over previous
//
#include <hip/hip_runtime.h>
#include <hip/hip_cooperative_groups.h>
#include <stdint.h>

typedef uint32_t u32;

#define DEV static __device__ __forceinline__

#define BATCH 512
#define CD    64
#define ZL    16
#define HID   512
#define H2D   256
#define NC    9
#define SLEN  64
#define L1    35

#define JAX_PARTITIONABLE 1

// ---------------- Threefry-2x32 (JAX key schedule, 20 rounds) ----------------
DEV void threefry2x32(u32 k0, u32 k1, u32 x0, u32 x1, u32 &o0, u32 &o1){
  const u32 ks2 = k0 ^ k1 ^ 0x1BD11BDAu;
#define TF_R(d) { x0 += x1; x1 = (x1 << (d)) | (x1 >> (32 - (d))); x1 ^= x0; }
  x0 += k0; x1 += k1;
  TF_R(13) TF_R(15) TF_R(26) TF_R(6)
  x0 += k1;  x1 += ks2 + 1u;
  TF_R(17) TF_R(29) TF_R(16) TF_R(24)
  x0 += ks2; x1 += k0 + 2u;
  TF_R(13) TF_R(15) TF_R(26) TF_R(6)
  x0 += k0;  x1 += k1 + 3u;
  TF_R(17) TF_R(29) TF_R(16) TF_R(24)
  x0 += k1;  x1 += ks2 + 4u;
  TF_R(13) TF_R(15) TF_R(26) TF_R(6)
  x0 += ks2; x1 += k0 + 5u;
#undef TF_R
  o0 = x0; o1 = x1;
}

DEV void step_key(int t, u32 &ka, u32 &kb){
#if JAX_PARTITIONABLE
  threefry2x32(0u, 42u, 0u, (u32)t, ka, kb);
#else
  u32 j0 = 2u*(u32)t, j1 = j0 + 1u, a0, a1;
  if (j0 < 64u){ threefry2x32(0u,42u, j0, 64u+j0, a0, a1); ka = a0; }
  else         { threefry2x32(0u,42u, j0-64u, j0, a0, a1); ka = a1; }
  if (j1 < 64u){ threefry2x32(0u,42u, j1, 64u+j1, a0, a1); kb = a0; }
  else         { threefry2x32(0u,42u, j1-64u, j1, a0, a1); kb = a1; }
#endif
}

DEV float rng_uniform(u32 ka, u32 kb, u32 f){
  u32 bits, o0, o1;
#if JAX_PARTITIONABLE
  threefry2x32(ka, kb, 0u, f, o0, o1);
  bits = o0 ^ o1;
#else
  const u32 HALF = (u32)(BATCH * NC / 2);
  if (f < HALF){ threefry2x32(ka, kb, f, f + HALF, o0, o1); bits = o0; }
  else         { threefry2x32(ka, kb, f - HALF, f, o0, o1); bits = o1; }
#endif
  u32 fb = (bits >> 9) | 0x3F800000u;
  float fv; __builtin_memcpy(&fv, &fb, 4);
  return fv - 1.0f;
}

// ---------------- ConvT1 (64->512, k=4, s=2, opad=1) + BN + LReLU ----------------
__global__ __launch_bounds__(256) void k_conv1(
    const float* __restrict__ z, const float* __restrict__ w1, const float* __restrict__ b1,
    const float* __restrict__ g1, const float* __restrict__ bt1, const float* __restrict__ m1,
    const float* __restrict__ v1, float* __restrict__ y1out)
{
  int t = blockIdx.x;
  int bg = blockIdx.y * 8;
  int tid = threadIdx.x;
  __shared__ float zsh[2][8][CD];
  int k0 = t & 1;
  int sA = (t - k0) >> 1, sB = sA - 1;
  bool vA = (sA >= 0 && sA < ZL), vB = (sB >= 0 && sB < ZL);
  for (int l = tid; l < 2*8*CD; l += 256){
    int p = l >> 9, bb = (l >> 6) & 7, i = l & 63;
    int s = p ? sB : sA; bool v = p ? vB : vA;
    zsh[p][bb][i] = v ? z[((bg + bb)*CD + i)*ZL + s] : 0.f;
  }
  __syncthreads();
  const float4* w1v = (const float4*)w1;
  for (int o = tid; o < HID; o += 256){
    float acc[8] = {0,0,0,0,0,0,0,0};
    for (int i = 0; i < CD; i++){
      float4 wv = w1v[i*HID + o];
      float wA = k0 ? wv.y : wv.x;
      float wB = k0 ? wv.w : wv.z;
      #pragma unroll
      for (int bb = 0; bb < 8; bb++)
        acc[bb] += zsh[0][bb][i]*wA + zsh[1][bb][i]*wB;
    }
    float xb = b1[o];
    float sc = g1[o] / sqrtf(v1[o] + 1e-5f);
    float mm = m1[o], be = bt1[o];
    #pragma unroll
    for (int bb = 0; bb < 8; bb++){
      float y = (acc[bb] + xb - mm)*sc + be;
      y = (y > 0.f) ? y : 0.2f*y;
      y1out[((bg + bb)*L1 + t)*HID + o] = y;
    }
  }
}

// ---------------- ConvT2 (512->256, k=4, s=2) + BN + LReLU -> xinT[t][c][b] ------
__global__ __launch_bounds__(256) void k_conv2(
    const float* __restrict__ y1, const float* __restrict__ w2, const float* __restrict__ b2,
    const float* __restrict__ g2, const float* __restrict__ bt2, const float* __restrict__ m2,
    const float* __restrict__ v2, float* __restrict__ xinT)
{
  int t = blockIdx.x;
  int bg = blockIdx.y * 8;
  int tid = threadIdx.x;
  __shared__ float ysh[2][8][HID];
  int k0 = t & 1;
  int sA = (t - k0) >> 1, sB = sA - 1;
  bool vB = (sB >= 0);
  for (int l = tid; l < 2*8*HID; l += 256){
    int p = l >> 12, bb = (l >> 9) & 7, o = l & 511;
    int s = p ? sB : sA; bool v = p ? vB : true;
    ysh[p][bb][o] = v ? y1[((bg + bb)*L1 + s)*HID + o] : 0.f;
  }
  __syncthreads();
  int c = tid;
  float acc[8] = {0,0,0,0,0,0,0,0};
  const float4* w2v = (const float4*)w2;
  for (int o4 = 0; o4 < HID; o4 += 4){
    float wA[4], wB[4];
    #pragma unroll
    for (int j = 0; j < 4; j++){
      float4 wv = w2v[(o4 + j)*H2D + c];
      wA[j] = k0 ? wv.y : wv.x;
      wB[j] = k0 ? wv.w : wv.z;
    }
    #pragma unroll
    for (int bb = 0; bb < 8; bb++){
      const float4 ya = *(const float4*)&ysh[0][bb][o4];
      const float4 yb = *(const float4*)&ysh[1][bb][o4];
      acc[bb] += ya.x*wA[0] + ya.y*wA[1] + ya.z*wA[2] + ya.w*wA[3]
               + yb.x*wB[0] + yb.y*wB[1] + yb.z*wB[2] + yb.w*wB[3];
    }
  }
  float xb = b2[c];
  float sc = g2[c] / sqrtf(v2[c] + 1e-5f);
  float mm = m2[c], be = bt2[c];
  float res[8];
  #pragma unroll
  for (int bb = 0; bb < 8; bb++){
    float y = (acc[bb] + xb - mm)*sc + be;
    res[bb] = (y > 0.f) ? y : 0.2f*y;
  }
  size_t base = (size_t)(t*H2D + c)*512 + bg;
  *(float4*)&xinT[base]     = make_float4(res[0],res[1],res[2],res[3]);
  *(float4*)&xinT[base + 4] = make_float4(res[4],res[5],res[6],res[7]);
}

// ---------------- h1_0 (transposed write h1T[n][b]) ------------------------------
__global__ __launch_bounds__(256) void k_h0(
    const float* __restrict__ se, const float* __restrict__ w, const float* __restrict__ bias,
    float* __restrict__ h1T)
{
  int b = blockIdx.x, tid = threadIdx.x;
  __shared__ float ssh[HID];
  for (int i = tid; i < HID; i += 256) ssh[i] = se[b*HID + i];
  __syncthreads();
  for (int j = tid; j < HID; j += 256){
    float acc = 0.f;
    for (int q = 0; q < HID; q++) acc += ssh[q] * w[j*HID + q];
    h1T[(size_t)j*512 + b] = acc + bias[j];
  }
}

// ---------------- prep: pad wih1 [1536][274]->[1536][320]; skelT[t][c][b] --------
__global__ __launch_bounds__(256) void k_prep(
    const float* __restrict__ wih1, const float* __restrict__ skel,
    float* __restrict__ wih1p, float* __restrict__ skelT)
{
  int i = blockIdx.x*256 + threadIdx.x;
  if (i < 1536*320){
    int n = i/320, k = i - n*320;
    wih1p[i] = (k < 274) ? wih1[n*274 + k] : 0.f;
  }
  if (i < SLEN*NC*512){
    int b = i & 511, r = i >> 9;
    int c = r % NC, tt = r / NC;
    skelT[i] = skel[((size_t)b*SLEN + tt)*NC + c];
  }
}

// ---------------- persistent recurrence kernel ------------------------------------
// grid 256 blocks x 256 threads, cooperative. ntile=blockIdx%32 (16 cols), bg=blockIdx/32.
// wave (64 lanes = 64 batch rows) handles 4 cols x 3 gates; weights via uniform scalar loads.
__global__ __launch_bounds__(256, 1) void k_persist(
    const float* __restrict__ xinT, const float* __restrict__ skelT,
    const float* __restrict__ wih1p, const float* __restrict__ whh1,
    const float* __restrict__ wih2,  const float* __restrict__ whh2,
    const float* __restrict__ bih1,  const float* __restrict__ bhh1,
    const float* __restrict__ bih2,  const float* __restrict__ bhh2,
    const float* __restrict__ nw,    const float* __restrict__ nbias,
    float* __restrict__ h1a, float* __restrict__ h1b,
    float* __restrict__ h2a, float* __restrict__ h2b,
    float* __restrict__ dout)
{
  cooperative_groups::grid_group grid = cooperative_groups::this_grid();
  const int tid  = threadIdx.x;
  const int lane = tid & 63;
  const int kq   = tid >> 6;                                   // wave id / k-phase
  const int wv   = __builtin_amdgcn_readfirstlane(kq);
  const int ntile = blockIdx.x & 31;
  const int bg    = blockIdx.x >> 5;
  const int bglob = bg*64 + lane;
  const int n0    = ntile*16 + wv*4;

  __shared__ float Abuf[2][64][66];   // [buf][b][k], stride 66 (2-way banks = free)
  __shared__ float out_sh[64][12];    // sampled feedback [b][c]
  __shared__ float h2_sh[32][64];     // logits staging chunk [n][b]

  int t = 0;
  const float *h1prev = nullptr, *h2prevB = nullptr, *h2samp = nullptr;
  float *h1new = nullptr, *h2new = nullptr;

  auto write_win = [&](int buf, const float* pre){
    #pragma unroll
    for (int j = 0; j < 16; j++) Abuf[buf][lane][j*4 + kq] = pre[j];
  };
  auto load_cat = [&](int w8, float* pre){
    #pragma unroll
    for (int j = 0; j < 16; j++){
      int kg = w8*64 + j*4 + kq;
      float v;
      if (kg < 9)        v = out_sh[lane][kg];
      else if (kg < 265) v = xinT[((size_t)(t*H2D + (kg-9)))*512 + bglob];
      else if (kg < 274) v = skelT[((size_t)(t*NC + (kg-265)))*512 + bglob];
      else               v = 0.f;
      pre[j] = v;
    }
  };
  auto load_h = [&](const float* H, int w8, float* pre){
    #pragma unroll
    for (int j = 0; j < 16; j++){
      int kg = w8*64 + j*4 + kq;
      pre[j] = H[(size_t)kg*512 + bglob];
    }
  };
  auto gemm_win = [&](int buf, const float* wbase, int ldw,
                      float* aR, float* aZ, float* aN){
    const float* Ar = &Abuf[buf][lane][0];
    const size_t g1 = (size_t)512*ldw, g2 = (size_t)1024*ldw;
    for (int k8 = 0; k8 < 64; k8 += 8){
      #pragma unroll
      for (int k2 = 0; k2 < 8; k2 += 2){
        float2 a = *(const float2*)&Ar[k8 + k2];
        #pragma unroll
        for (int c = 0; c < 4; c++){
          const float* wr = wbase + (size_t)c*ldw + (k8 + k2);
          aR[c] += a.x*wr[0]    + a.y*wr[1];
          aZ[c] += a.x*wr[g1]   + a.y*wr[g1+1];
          aN[c] += a.x*wr[g2]   + a.y*wr[g2+1];
        }
      }
    }
  };
  auto run_cat = [&](int NW, const float* W, int ldw, float* aR, float* aZ, float* aN){
    float pre[16];
    load_cat(0, pre); write_win(0, pre); __syncthreads();
    for (int w8 = 0; w8 < NW; w8++){
      float nxt[16];
      if (w8 + 1 < NW) load_cat(w8 + 1, nxt);
      gemm_win(w8 & 1, W + (size_t)n0*ldw + w8*64, ldw, aR, aZ, aN);
      if (w8 + 1 < NW) write_win((w8 + 1) & 1, nxt);
      __syncthreads();
    }
  };
  auto run_h = [&](int NW, const float* H, const float* W, int ldw,
                   float* aR, float* aZ, float* aN){
    float pre[16];
    load_h(H, 0, pre); write_win(0, pre); __syncthreads();
    for (int w8 = 0; w8 < NW; w8++){
      float nxt[16];
      if (w8 + 1 < NW) load_h(H, w8 + 1, nxt);
      gemm_win(w8 & 1, W + (size_t)n0*ldw + w8*64, ldw, aR, aZ, aN);
      if (w8 + 1 < NW) write_win((w8 + 1) & 1, nxt);
      __syncthreads();
    }
  };

  auto sample = [&](){
    if (t == 0){
      for (int idx = tid; idx < 576; idx += 256) out_sh[idx & 63][idx >> 6] = 0.f;
      __syncthreads();
      return;
    }
    float lacc[3] = {0.f, 0.f, 0.f};
    for (int nc = 0; nc < 512; nc += 32){
      #pragma unroll
      for (int j = 0; j < 8; j++){
        int e = j*256 + tid;
        h2_sh[e >> 6][e & 63] = h2samp[(size_t)(nc + (e >> 6))*512 + bg*64 + (e & 63)];
      }
      __syncthreads();
      int slot = 0;
      for (int idx = tid; idx < 576; idx += 256, slot++){
        int c = idx >> 6, bl = idx & 63;
        const float* wr = nw + c*512 + nc;
        float s = lacc[slot];
        #pragma unroll 8
        for (int nn = 0; nn < 32; nn++) s += h2_sh[nn][bl]*wr[nn];
        lacc[slot] = s;
      }
      __syncthreads();
    }
    int slot = 0;
    for (int idx = tid; idx < 576; idx += 256, slot++){
      int c = idx >> 6, bl = idx & 63;
      float logit = lacc[slot] + nbias[c];
      if (ntile == 0) dout[((size_t)(bg*64 + bl)*SLEN + (t-1))*NC + c] = logit;
      if (t <= 63){
        u32 ka, kb2; step_key(t-1, ka, kb2);
        float r = rng_uniform(ka, kb2, (u32)((bg*64 + bl)*NC + c));
        float sg = 1.f/(1.f + expf(-logit));
        out_sh[bl][c] = (sg - r > 0.f) ? 1.f : 0.f;
      }
    }
    __syncthreads();
  };

  for (t = 0; t <= 64; t++){
    h1prev  = (t & 1) ? h1b : h1a;
    h1new   = (t & 1) ? h1a : h1b;
    h2new   = (t & 1) ? h2b : h2a;
    h2prevB = (t == 0) ? h1new : ((t & 1) ? h2a : h2b);
    h2samp  = ((t-1) & 1) ? h2b : h2a;

    sample();
    if (t == 64) break;

    // ---- GRU1 ----
    float aR[4] = {0,0,0,0}, aZ[4] = {0,0,0,0}, aI[4] = {0,0,0,0}, aH[4] = {0,0,0,0};
    run_cat(5, wih1p, 320, aR, aZ, aI);
    run_h(8, h1prev, whh1, 512, aR, aZ, aH);
    #pragma unroll
    for (int c = 0; c < 4; c++){
      int n = n0 + c;
      float r  = 1.f/(1.f + expf(-(aR[c] + bih1[n] + bhh1[n])));
      float z  = 1.f/(1.f + expf(-(aZ[c] + bih1[512+n] + bhh1[512+n])));
      float nn = tanhf(aI[c] + bih1[1024+n] + r*(aH[c] + bhh1[1024+n]));
      float hp = h1prev[(size_t)n*512 + bglob];
      h1new[(size_t)n*512 + bglob] = (1.f - z)*nn + z*hp;
    }
    grid.sync();

    // ---- GRU2 ----
    float cR[4] = {0,0,0,0}, cZ[4] = {0,0,0,0}, cI[4] = {0,0,0,0}, cH[4] = {0,0,0,0};
    run_h(8, h1new,   wih2, 512, cR, cZ, cI);
    run_h(8, h2prevB, whh2, 512, cR, cZ, cH);
    #pragma unroll
    for (int c = 0; c < 4; c++){
      int n = n0 + c;
      float r  = 1.f/(1.f + expf(-(cR[c] + bih2[n] + bhh2[n])));
      float z  = 1.f/(1.f + expf(-(cZ[c] + bih2[512+n] + bhh2[512+n])));
      float nn = tanhf(cI[c] + bih2[1024+n] + r*(cH[c] + bhh2[1024+n]));
      float hp = h2prevB[(size_t)n*512 + bglob];
      h2new[(size_t)n*512 + bglob] = (1.f - z)*nn + z*hp;
    }
    grid.sync();
  }
}

// ---------------- host ----------------
extern "C" void kernel_launch(void* const* d_in, const int* in_sizes, int n_in,
                              void* d_out, int out_size, void* d_ws, size_t ws_size,
                              hipStream_t stream) {
  (void)in_sizes; (void)n_in; (void)out_size; (void)ws_size;
  const float* z       = (const float*)d_in[0];
  const float* skel    = (const float*)d_in[2];
  const float* se      = (const float*)d_in[3];
  const float* ct1_w   = (const float*)d_in[6];
  const float* ct1_b   = (const float*)d_in[7];
  const float* bn1_g   = (const float*)d_in[8];
  const float* bn1_b   = (const float*)d_in[9];
  const float* bn1_m   = (const float*)d_in[10];
  const float* bn1_v   = (const float*)d_in[11];
  const float* ct2_w   = (const float*)d_in[12];
  const float* ct2_b   = (const float*)d_in[13];
  const float* bn2_g   = (const float*)d_in[14];
  const float* bn2_b   = (const float*)d_in[15];
  const float* bn2_m   = (const float*)d_in[16];
  const float* bn2_v   = (const float*)d_in[17];
  const float* hfc_w   = (const float*)d_in[18];
  const float* hfc_b   = (const float*)d_in[19];
  const float* g1_wih  = (const float*)d_in[20];
  const float* g1_whh  = (const float*)d_in[21];
  const float* g1_bih  = (const float*)d_in[22];
  const float* g1_bhh  = (const float*)d_in[23];
  const float* g2_wih  = (const float*)d_in[24];
  const float* g2_whh  = (const float*)d_in[25];
  const float* g2_bih  = (const float*)d_in[26];
  const float* g2_bhh  = (const float*)d_in[27];
  const float* nfc_w   = (const float*)d_in[28];
  const float* nfc_b   = (const float*)d_in[29];

  float* ws = (float*)d_ws;
  // conv phase:
  float* y1   = ws;                     // 512*35*512   = 9,175,040 floats
  float* xinT = ws + 9175040;           // 64*256*512   = 8,388,608 floats
  // recurrence phase (reuses y1 region, written only after conv2 completes):
  float* wih1p = ws;                    // 1536*320 = 491,520
  float* skelT = ws + 491520;           // 64*9*512 = 294,912
  float* h1a   = ws + 786432;           // 262,144 each
  float* h1b   = ws + 1048576;
  float* h2a   = ws + 1310720;
  float* h2b   = ws + 1572864;          // ends at 1,835,008 < 9,175,040 ✓
  float* dout  = (float*)d_out;

  k_conv1<<<dim3(L1, BATCH/8), 256, 0, stream>>>(z, ct1_w, ct1_b, bn1_g, bn1_b, bn1_m, bn1_v, y1);
  k_conv2<<<dim3(SLEN, BATCH/8), 256, 0, stream>>>(y1, ct2_w, ct2_b, bn2_g, bn2_b, bn2_m, bn2_v, xinT);
  k_h0<<<BATCH, 256, 0, stream>>>(se, hfc_w, hfc_b, h1a);
  k_prep<<<1920, 256, 0, stream>>>(g1_wih, skel, wih1p, skelT);

  void* args[] = {
    (void*)&xinT, (void*)&skelT, (void*)&wih1p, (void*)&g1_whh,
    (void*)&g2_wih, (void*)&g2_whh, (void*)&g1_bih, (void*)&g1_bhh,
    (void*)&g2_bih, (void*)&g2_bhh, (void*)&nfc_w, (void*)&nfc_b,
    (void*)&h1a, (void*)&h1b, (void*)&h2a, (void*)&h2b, (void*)&dout
  };
  hipLaunchCooperativeKernel((const void*)k_persist, dim3(256), dim3(256), args, 0, stream);
}